// Round 8
// baseline (118.734 us; speedup 1.0000x reference)
//
#include <hip/hip_runtime.h>
#include <stdint.h>

// Problem constants
#define B_    4
#define CQ_   256
#define CKV_  256
#define NQ_   2048
#define NKV_  2048
#define H_    8
#define DK_   64
#define HD_   512   // H_*DK_

typedef __attribute__((ext_vector_type(8))) short bf16x8;
typedef __attribute__((ext_vector_type(4))) float f32x4;

__device__ __forceinline__ short f2bf(float f) {
    unsigned u = __builtin_bit_cast(unsigned, f);
    u = (u + 0x7FFFu + ((u >> 16) & 1u)) >> 16;   // RNE truncate to bf16
    return (short)u;
}

__device__ __forceinline__ bf16x8 cvt8(const float* p) {
    const f32x4 v0 = *(const f32x4*)p;
    const f32x4 v1 = *(const f32x4*)(p + 4);
    bf16x8 o;
    o[0] = f2bf(v0.x); o[1] = f2bf(v0.y); o[2] = f2bf(v0.z); o[3] = f2bf(v0.w);
    o[4] = f2bf(v1.x); o[5] = f2bf(v1.y); o[6] = f2bf(v1.z); o[7] = f2bf(v1.w);
    return o;
}

#define MFMA16(a, b, c) __builtin_amdgcn_mfma_f32_16x16x32_bf16((a), (b), (c), 0, 0, 0)

// -------------------------------------------------------------------------
// Kernel 1: gram + pq folds. 512-thread (8-wave) blocks, 384 blocks.
//  [0,256):   Gram. 32x32 tiles. 8-wave split-K (K=256 each): doubles
//             waves/SIMD (1->2) vs round-7's 4-wave K=512 — the K-loop is
//             L2-latency-bound at 1 wave/SIMD with only dbuf-depth ILP.
//             G[b][c][c'] = (1/64) sum_n x[c][n] x[c'][n] -> bf16.
//  [256,384): pq folds (first 4 waves only; tiny):
//     lb<64:  P[c][h*256+c'] = sum_d Wo[c][h64+d]*Wv[h64+d][c']
//     else:   Qt[h*256+cq][c''] = sum_d Wk[h64+d][c'']*Wq[h64+d][cq]
// -------------------------------------------------------------------------
__global__ __launch_bounds__(512) void gram_pq_kernel(
    const float* __restrict__ x_kv,
    const float* __restrict__ Wq,
    const float* __restrict__ Wk,
    const float* __restrict__ Wv,
    const float* __restrict__ Wo,
    unsigned short* __restrict__ Gsum,
    unsigned short* __restrict__ P,
    unsigned short* __restrict__ Qt)
{
    const int tid = threadIdx.x;
    const int bid = blockIdx.x;
    const int w = tid >> 6, L = tid & 63;     // w: 0..7
    const int r16 = L & 15, q = L >> 4;
    __shared__ float red[8][32][36];          // 36.8 KB

    if (bid < 256) {
        // ---- Gram, 8-wave split-K ----
        const int t = bid & 63;
        const int b = bid >> 6;
        const int tm = (t >> 3) * 32;
        const int tn = (t & 7) * 32;

        const float* Xb = x_kv + (size_t)b * CKV_ * NKV_;
        const float* A0 = Xb + (size_t)(tm + r16) * NKV_;
        const float* A1 = A0 + (size_t)16 * NKV_;
        const float* B0 = Xb + (size_t)(tn + r16) * NKV_;
        const float* B1 = B0 + (size_t)16 * NKV_;
        const int k0 = w * 256 + q * 8;

        f32x4 acc[2][2];
#pragma unroll
        for (int mi = 0; mi < 2; ++mi)
#pragma unroll
            for (int ni = 0; ni < 2; ++ni) acc[mi][ni] = (f32x4){0.f,0.f,0.f,0.f};

        bf16x8 aC[2], bC[2];
        aC[0] = cvt8(A0 + k0);
        aC[1] = cvt8(A1 + k0);
        bC[0] = cvt8(B0 + k0);
        bC[1] = cvt8(B1 + k0);

#pragma unroll
        for (int kk = 0; kk < 8; ++kk) {
            bf16x8 aN[2], bN[2];
            if (kk < 7) {
                const int ko = k0 + (kk + 1) * 32;
                aN[0] = cvt8(A0 + ko);
                aN[1] = cvt8(A1 + ko);
                bN[0] = cvt8(B0 + ko);
                bN[1] = cvt8(B1 + ko);
            }
            acc[0][0] = MFMA16(aC[0], bC[0], acc[0][0]);
            acc[0][1] = MFMA16(aC[0], bC[1], acc[0][1]);
            acc[1][0] = MFMA16(aC[1], bC[0], acc[1][0]);
            acc[1][1] = MFMA16(aC[1], bC[1], acc[1][1]);
            aC[0] = aN[0]; aC[1] = aN[1]; bC[0] = bN[0]; bC[1] = bN[1];
        }

#pragma unroll
        for (int mi = 0; mi < 2; ++mi)
#pragma unroll
            for (int ni = 0; ni < 2; ++ni)
#pragma unroll
                for (int r = 0; r < 4; ++r)
                    red[w][mi * 16 + q * 4 + r][ni * 16 + r16] = acc[mi][ni][r];
        __syncthreads();

        if (tid < 256) {
            const int m  = tid >> 3;              // 0..31
            const int n4 = (tid & 7) * 4;         // 0..28
            f32x4 s = *(const f32x4*)&red[0][m][n4];
#pragma unroll
            for (int ww = 1; ww < 8; ++ww) {
                const f32x4 v = *(const f32x4*)&red[ww][m][n4];
                s.x += v.x; s.y += v.y; s.z += v.z; s.w += v.w;
            }
            const float sc = 1.0f / 64.0f;
            ushort4 o;
            o.x = (unsigned short)f2bf(s.x * sc);
            o.y = (unsigned short)f2bf(s.y * sc);
            o.z = (unsigned short)f2bf(s.z * sc);
            o.w = (unsigned short)f2bf(s.w * sc);
            *(ushort4*)(Gsum + (size_t)b * 65536 + (size_t)(tm + m) * 256 + tn + n4) = o;
        }
        return;
    }

    // ---- pq part (first 4 waves only) ----
    if (tid >= 256) return;
    const int lb0 = bid - 256;
    const bool isP = (lb0 < 64);
    const int lb = isP ? lb0 : lb0 - 64;
    const int h = lb >> 3;
    const int t = lb & 7;
    const int tm = (t >> 1) * 64;
    const int tn = (t & 1) * 128;
    const int wm = (w >> 1) * 32, wn = (w & 1) * 64;

    f32x4 acc[2][4];
#pragma unroll
    for (int mi = 0; mi < 2; ++mi)
#pragma unroll
        for (int ni = 0; ni < 4; ++ni) acc[mi][ni] = (f32x4){0.f,0.f,0.f,0.f};

#pragma unroll
    for (int kk = 0; kk < 2; ++kk) {
        const int d0 = kk * 32 + q * 8;
        bf16x8 a[2], bb[4];
        if (isP) {
#pragma unroll
            for (int mi = 0; mi < 2; ++mi) {
                const int m = tm + wm + mi * 16 + r16;
                a[mi] = cvt8(Wo + (size_t)m * HD_ + h * 64 + d0);
            }
#pragma unroll
            for (int ni = 0; ni < 4; ++ni) {
                const int n = tn + wn + ni * 16 + r16;
#pragma unroll
                for (int j = 0; j < 8; ++j)
                    bb[ni][j] = f2bf(Wv[(size_t)(h * 64 + d0 + j) * CKV_ + n]);
            }
        } else {
#pragma unroll
            for (int mi = 0; mi < 2; ++mi) {
                const int m = tm + wm + mi * 16 + r16;
#pragma unroll
                for (int j = 0; j < 8; ++j)
                    a[mi][j] = f2bf(Wq[(size_t)(h * 64 + d0 + j) * CQ_ + m]);
            }
#pragma unroll
            for (int ni = 0; ni < 4; ++ni) {
                const int n = tn + wn + ni * 16 + r16;
#pragma unroll
                for (int j = 0; j < 8; ++j)
                    bb[ni][j] = f2bf(Wk[(size_t)(h * 64 + d0 + j) * CKV_ + n]);
            }
        }
#pragma unroll
        for (int mi = 0; mi < 2; ++mi)
#pragma unroll
            for (int ni = 0; ni < 4; ++ni)
                acc[mi][ni] = MFMA16(a[mi], bb[ni], acc[mi][ni]);
    }

#pragma unroll
    for (int mi = 0; mi < 2; ++mi)
#pragma unroll
        for (int ni = 0; ni < 4; ++ni)
#pragma unroll
            for (int r = 0; r < 4; ++r) {
                const int m = tm + wm + mi * 16 + q * 4 + r;
                const int n = tn + wn + ni * 16 + r16;
                if (isP)  P [(size_t)m * 2048 + h * 256 + n] = (unsigned short)f2bf(acc[mi][ni][r]);
                else      Qt[((size_t)h * 256 + m) * 256 + n] = (unsigned short)f2bf(acc[mi][ni][r]);
            }
}

// -------------------------------------------------------------------------
// Kernel 2: zgemm.  Zt_b[cq][h*256+c'] = sum_{c''} Qt[(h,cq)][c'']*Gs_b[c'][c'']
// 64x64 tiles, grid (16,8,4)=512 blocks.  Double-buffered K-loop.
// (byte-identical to round 7)
// -------------------------------------------------------------------------
__global__ __launch_bounds__(256) void zgemm_kernel(
    const unsigned short* __restrict__ Qt,
    const unsigned short* __restrict__ Gsum,
    unsigned short* __restrict__ Zt)
{
    const int t = blockIdx.x;   // 0..15
    const int h = blockIdx.y;
    const int b = blockIdx.z;
    const int tid = threadIdx.x;
    const int w = tid >> 6, L = tid & 63;
    const int r16 = L & 15, q = L >> 4;
    const int tm = (t >> 2) * 64;
    const int tn = (t & 3) * 64;
    const int wm = (w >> 1) * 32, wn = (w & 1) * 32;

    const unsigned short* Qh = Qt + (size_t)h * 65536;
    const unsigned short* Gb = Gsum + (size_t)b * 65536;
    const unsigned short* A0 = Qh + (size_t)(tm + wm + r16) * 256;
    const unsigned short* A1 = A0 + 16 * 256;
    const unsigned short* B0 = Gb + (size_t)(tn + wn + r16) * 256;
    const unsigned short* B1 = B0 + 16 * 256;
    const int k0 = q * 8;

    f32x4 acc[2][2];
#pragma unroll
    for (int mi = 0; mi < 2; ++mi)
#pragma unroll
        for (int ni = 0; ni < 2; ++ni) acc[mi][ni] = (f32x4){0.f,0.f,0.f,0.f};

    bf16x8 aC[2], bC[2];
    aC[0] = *(const bf16x8*)(A0 + k0);
    aC[1] = *(const bf16x8*)(A1 + k0);
    bC[0] = *(const bf16x8*)(B0 + k0);
    bC[1] = *(const bf16x8*)(B1 + k0);

#pragma unroll
    for (int kk = 0; kk < 8; ++kk) {
        bf16x8 aN[2], bN[2];
        if (kk < 7) {
            const int ko = k0 + (kk + 1) * 32;
            aN[0] = *(const bf16x8*)(A0 + ko);
            aN[1] = *(const bf16x8*)(A1 + ko);
            bN[0] = *(const bf16x8*)(B0 + ko);
            bN[1] = *(const bf16x8*)(B1 + ko);
        }
        acc[0][0] = MFMA16(aC[0], bC[0], acc[0][0]);
        acc[0][1] = MFMA16(aC[0], bC[1], acc[0][1]);
        acc[1][0] = MFMA16(aC[1], bC[0], acc[1][0]);
        acc[1][1] = MFMA16(aC[1], bC[1], acc[1][1]);
        aC[0] = aN[0]; aC[1] = aN[1]; bC[0] = bN[0]; bC[1] = bN[1];
    }

    unsigned short* Zb = Zt + (size_t)b * 256 * 2048;
#pragma unroll
    for (int mi = 0; mi < 2; ++mi)
#pragma unroll
        for (int ni = 0; ni < 2; ++ni)
#pragma unroll
            for (int r = 0; r < 4; ++r) {
                const int m = tm + wm + mi * 16 + q * 4 + r;       // cq
                const int n = tn + wn + ni * 16 + r16;             // c'
                Zb[(size_t)m * 2048 + h * 256 + n] = (unsigned short)f2bf(acc[mi][ni][r]);
            }
}

// -------------------------------------------------------------------------
// Kernel 3: ngemm.  N[b][c][cq] = sum_k P[c][k]*Zt_b[cq][k]
// 32x32 tiles, grid (64,4)=256 blocks of 512 threads; 8-wave split-K
// (K=256 each -> 2 waves/SIMD, doubles latency hiding) + 8-way LDS reduce.
// -------------------------------------------------------------------------
__global__ __launch_bounds__(512) void ngemm_kernel(
    const unsigned short* __restrict__ P,
    const unsigned short* __restrict__ Zt,
    unsigned short* __restrict__ Nbf)
{
    const int t  = blockIdx.x;            // 0..63
    const int b  = blockIdx.y;
    const int tid = threadIdx.x;
    const int w = tid >> 6, L = tid & 63; // w: 0..7
    const int r16 = L & 15, q = L >> 4;
    const int tm = (t >> 3) * 32;         // c
    const int tn = (t & 7) * 32;          // cq

    const unsigned short* Zb = Zt + (size_t)b * 256 * 2048;
    const unsigned short* A0 = P  + (size_t)(tm + r16) * 2048;
    const unsigned short* A1 = A0 + (size_t)16 * 2048;
    const unsigned short* B0 = Zb + (size_t)(tn + r16) * 2048;
    const unsigned short* B1 = B0 + (size_t)16 * 2048;
    const int k0 = w * 256 + q * 8;

    f32x4 acc[2][2];
#pragma unroll
    for (int mi = 0; mi < 2; ++mi)
#pragma unroll
        for (int ni = 0; ni < 2; ++ni) acc[mi][ni] = (f32x4){0.f,0.f,0.f,0.f};

    bf16x8 aC[2], bC[2];
    aC[0] = *(const bf16x8*)(A0 + k0);
    aC[1] = *(const bf16x8*)(A1 + k0);
    bC[0] = *(const bf16x8*)(B0 + k0);
    bC[1] = *(const bf16x8*)(B1 + k0);

#pragma unroll
    for (int kk = 0; kk < 8; ++kk) {
        bf16x8 aN[2], bN[2];
        if (kk < 7) {
            const int ko = k0 + (kk + 1) * 32;
            aN[0] = *(const bf16x8*)(A0 + ko);
            aN[1] = *(const bf16x8*)(A1 + ko);
            bN[0] = *(const bf16x8*)(B0 + ko);
            bN[1] = *(const bf16x8*)(B1 + ko);
        }
        acc[0][0] = MFMA16(aC[0], bC[0], acc[0][0]);
        acc[0][1] = MFMA16(aC[0], bC[1], acc[0][1]);
        acc[1][0] = MFMA16(aC[1], bC[0], acc[1][0]);
        acc[1][1] = MFMA16(aC[1], bC[1], acc[1][1]);
        aC[0] = aN[0]; aC[1] = aN[1]; bC[0] = bN[0]; bC[1] = bN[1];
    }

    __shared__ float red[8][32][36];      // 36.8 KB
#pragma unroll
    for (int mi = 0; mi < 2; ++mi)
#pragma unroll
        for (int ni = 0; ni < 2; ++ni)
#pragma unroll
            for (int r = 0; r < 4; ++r)
                red[w][mi * 16 + q * 4 + r][ni * 16 + r16] = acc[mi][ni][r];
    __syncthreads();

    if (tid < 256) {
        const int m  = tid >> 3;              // 0..31 (c)
        const int n4 = (tid & 7) * 4;         // 0..28 (cq)
        f32x4 s = *(const f32x4*)&red[0][m][n4];
#pragma unroll
        for (int ww = 1; ww < 8; ++ww) {
            const f32x4 v = *(const f32x4*)&red[ww][m][n4];
            s.x += v.x; s.y += v.y; s.z += v.z; s.w += v.w;
        }
        ushort4 o;
        o.x = (unsigned short)f2bf(s.x);
        o.y = (unsigned short)f2bf(s.y);
        o.z = (unsigned short)f2bf(s.z);
        o.w = (unsigned short)f2bf(s.w);
        *(ushort4*)(Nbf + (size_t)b * 65536 + (size_t)(tm + m) * 256 + tn + n4) = o;
    }
}

// -------------------------------------------------------------------------
// Kernel 4: final.  out[b][c][n] = g*sum_cq Nbf[b][c][cq]*x_q[b][cq][n] + x_q[b][c][n]
// B-operand assembled directly from f32 x_q.  64x64 tiles, grid (32,4,4).
// (byte-identical to round 7)
// -------------------------------------------------------------------------
__global__ __launch_bounds__(256) void final_kernel(
    const unsigned short* __restrict__ Nbf,
    const float* __restrict__ x_q,
    const float* __restrict__ gamma,
    float* __restrict__ out)
{
    const int nblk = blockIdx.x * 64;
    const int cblk = blockIdx.y * 64;
    const int b    = blockIdx.z;
    const int tid  = threadIdx.x;
    const int w = tid >> 6, L = tid & 63;
    const int r16 = L & 15, q = L >> 4;
    const int wc = (w >> 1) * 32;
    const int wn = (w & 1) * 32;

    const unsigned short* Nb = Nbf + (size_t)b * 65536;
    const float* Xb = x_q + (size_t)b * CQ_ * NQ_;   // [cq][n]
    const float g = gamma[0];

    const unsigned short* A0 = Nb + (size_t)(cblk + wc + r16) * 256;
    const unsigned short* A1 = A0 + 16 * 256;
    const int n0 = nblk + wn + r16;     // B row for fragment 0
    const int n1 = n0 + 16;             // B row for fragment 1
    const int k0 = q * 8;

    f32x4 acc[2][2];
#pragma unroll
    for (int mi = 0; mi < 2; ++mi)
#pragma unroll
        for (int ni = 0; ni < 2; ++ni) acc[mi][ni] = (f32x4){0.f,0.f,0.f,0.f};

    bf16x8 aC[2], bC[2];
    aC[0] = *(const bf16x8*)(A0 + k0);
    aC[1] = *(const bf16x8*)(A1 + k0);
#pragma unroll
    for (int j = 0; j < 8; ++j) {
        bC[0][j] = f2bf(Xb[(size_t)(k0 + j) * NQ_ + n0]);
        bC[1][j] = f2bf(Xb[(size_t)(k0 + j) * NQ_ + n1]);
    }

#pragma unroll
    for (int kk = 0; kk < 8; ++kk) {
        bf16x8 aN[2], bN[2];
        if (kk < 7) {
            const int ko = k0 + (kk + 1) * 32;
            aN[0] = *(const bf16x8*)(A0 + ko);
            aN[1] = *(const bf16x8*)(A1 + ko);
#pragma unroll
            for (int j = 0; j < 8; ++j) {
                bN[0][j] = f2bf(Xb[(size_t)(ko + j) * NQ_ + n0]);
                bN[1][j] = f2bf(Xb[(size_t)(ko + j) * NQ_ + n1]);
            }
        }
        acc[0][0] = MFMA16(aC[0], bC[0], acc[0][0]);
        acc[0][1] = MFMA16(aC[0], bC[1], acc[0][1]);
        acc[1][0] = MFMA16(aC[1], bC[0], acc[1][0]);
        acc[1][1] = MFMA16(aC[1], bC[1], acc[1][1]);
        aC[0] = aN[0]; aC[1] = aN[1]; bC[0] = bN[0]; bC[1] = bN[1];
    }

#pragma unroll
    for (int mi = 0; mi < 2; ++mi)
#pragma unroll
        for (int ni = 0; ni < 2; ++ni)
#pragma unroll
            for (int r = 0; r < 4; ++r) {
                const int c = cblk + wc + mi * 16 + q * 4 + r;
                const int n = nblk + wn + ni * 16 + r16;
                const size_t idx = ((size_t)b * CQ_ + c) * NQ_ + n;
                out[idx] = g * acc[mi][ni][r] + Xb[(size_t)c * NQ_ + n];
            }
}

// -------------------------------------------------------------------------
extern "C" void kernel_launch(void* const* d_in, const int* in_sizes, int n_in,
                              void* d_out, int out_size, void* d_ws, size_t ws_size,
                              hipStream_t stream) {
    const float* x_q   = (const float*)d_in[0];
    const float* x_kv  = (const float*)d_in[1];
    const float* Wq    = (const float*)d_in[2];
    const float* Wk    = (const float*)d_in[3];
    const float* Wv    = (const float*)d_in[4];
    const float* Wo    = (const float*)d_in[5];
    const float* gamma = (const float*)d_in[6];
    float* out = (float*)d_out;

    char* ws = (char*)d_ws;
    // ws layout (bytes):
    //   Gsum bf16 [4][256][256]        0 ..   524288
    //   P    bf16 [256][2048]     524288 ..  1572864
    //   Qt   bf16 [2048][256]    1572864 ..  2621440
    //   Zt   bf16 [4][256][2048] 2621440 ..  6815744
    //   Nbf  bf16 [4][256][256]  6815744 ..  7340032
    unsigned short* Gsum = (unsigned short*)(ws);
    unsigned short* P    = (unsigned short*)(ws + 524288);
    unsigned short* Qt   = (unsigned short*)(ws + 1572864);
    unsigned short* Zt   = (unsigned short*)(ws + 2621440);
    unsigned short* Nbf  = (unsigned short*)(ws + 6815744);

    gram_pq_kernel<<<dim3(384), 512, 0, stream>>>(x_kv, Wq, Wk, Wv, Wo,
                                                  Gsum, P, Qt);
    zgemm_kernel<<<dim3(16, 8, 4), 256, 0, stream>>>(Qt, Gsum, Zt);
    ngemm_kernel<<<dim3(64, 4), 512, 0, stream>>>(P, Zt, Nbf);
    final_kernel<<<dim3(32, 4, 4), 256, 0, stream>>>(Nbf, x_q, gamma, out);
}